// Round 3
// baseline (201.905 us; speedup 1.0000x reference)
//
#include <hip/hip_runtime.h>
#include <hip/hip_bf16.h>
#include <stdint.h>

#define B_SZ 8192
#define D_SZ 512
#define U_SZ 512
#define M_SZ 16
#define K_SZ 64

typedef short bf16x8 __attribute__((ext_vector_type(8)));
typedef float f32x4 __attribute__((ext_vector_type(4)));

__device__ __forceinline__ unsigned short f2bf(float f) {
  union { float f; unsigned u; } v; v.f = f;
  unsigned r = v.u + 0x7fffu + ((v.u >> 16) & 1u);
  return (unsigned short)(r >> 16);
}

// async global->LDS, 16B per lane; LDS dest = wave-uniform base + lane*16
__device__ __forceinline__ void async16(const void* gptr, void* ldsptr) {
  __builtin_amdgcn_global_load_lds(
      (const __attribute__((address_space(1))) unsigned int*)gptr,
      (__attribute__((address_space(3))) unsigned int*)ldsptr,
      16, 0, 0);
}

// ---------------- x f32 -> bf16 ----------------
__global__ __launch_bounds__(256) void cvt_x(const float* __restrict__ x,
                                             unsigned short* __restrict__ xb) {
  int i = (blockIdx.x * 256 + threadIdx.x) * 4;
  float4 v = *(const float4*)(x + i);
  ushort4 o;
  o.x = f2bf(v.x); o.y = f2bf(v.y); o.z = f2bf(v.z); o.w = f2bf(v.w);
  *(ushort4*)(xb + i) = o;
}

// ------- generic [m][Dd][Uu] f32 -> [m][Uu][Dd] bf16 tile transpose -------
// grid (Uu/64, Dd/32, m), 256 threads
__global__ __launch_bounds__(256) void cvt_tr(const float* __restrict__ kin,
                                              unsigned short* __restrict__ kT,
                                              int Dd, int Uu) {
  __shared__ float tf[32][65];
  int m = blockIdx.z, d0 = blockIdx.y * 32, u0 = blockIdx.x * 64;
  int t = threadIdx.x;
  {
    int dr = t >> 4, uc = t & 15;
    const float* src = kin + ((size_t)m * Dd + d0 + dr) * Uu + u0 + uc * 4;
    float4 a = *(const float4*)src;
    float4 b = *(const float4*)(src + (size_t)16 * Uu);
    tf[dr][uc * 4 + 0] = a.x; tf[dr][uc * 4 + 1] = a.y;
    tf[dr][uc * 4 + 2] = a.z; tf[dr][uc * 4 + 3] = a.w;
    tf[dr + 16][uc * 4 + 0] = b.x; tf[dr + 16][uc * 4 + 1] = b.y;
    tf[dr + 16][uc * 4 + 2] = b.z; tf[dr + 16][uc * 4 + 3] = b.w;
  }
  __syncthreads();
  {
    int ur = t >> 2, dc = t & 3;
    unsigned short* dst = kT + ((size_t)m * Uu + u0 + ur) * Dd + d0 + dc * 8;
    ushort4 lo, hi;
    lo.x = f2bf(tf[dc * 8 + 0][ur]); lo.y = f2bf(tf[dc * 8 + 1][ur]);
    lo.z = f2bf(tf[dc * 8 + 2][ur]); lo.w = f2bf(tf[dc * 8 + 3][ur]);
    hi.x = f2bf(tf[dc * 8 + 4][ur]); hi.y = f2bf(tf[dc * 8 + 5][ur]);
    hi.z = f2bf(tf[dc * 8 + 6][ur]); hi.w = f2bf(tf[dc * 8 + 7][ur]);
    *(ushort4*)dst = lo;
    *(ushort4*)(dst + 4) = hi;
  }
}

// ------- keyv[b,64] = xb @ wkT^T + key_bias  (MFMA GEMM) -------
// grid 64 blocks, 256 thr, 4 waves; block = 128 rows x 64 cols; wave = 32 rows.
__global__ __launch_bounds__(256) void keyv_gemm(
    const unsigned short* __restrict__ xb, const unsigned short* __restrict__ wkT,
    const float* __restrict__ key_bias, float* __restrict__ keyv) {
  __shared__ unsigned short sW[64 * 512];  // 64 KB (whole wkT)
  __shared__ unsigned short sA[128 * 64];  // 16 KB
  int t = threadIdx.x, w = t >> 6, l = t & 63;
  int b0 = blockIdx.x * 128;
  // stage whole wkT: 64 rows x 1 KB each, 16 chunks/wave, swizzled
#pragma unroll
  for (int c = 0; c < 16; ++c) {
    int ch = w * 16 + c;  // row
    async16(wkT + (size_t)ch * 512 + (size_t)(l ^ (ch & 7)) * 8,
            (char*)sW + ch * 1024);
  }
  int rbase = w * 32;
  int lane16 = l & 15, quad = l >> 4, sw = lane16 & 7;
  f32x4 acc[2][4];
#pragma unroll
  for (int i = 0; i < 2; ++i)
#pragma unroll
    for (int j = 0; j < 4; ++j) acc[i][j] = (f32x4){0.f, 0.f, 0.f, 0.f};

  for (int kt = 0; kt < 8; ++kt) {
    __syncthreads();
    // stage A 128x64 (16 chunks, 4/wave), swizzled
#pragma unroll
    for (int c = 0; c < 4; ++c) {
      int ch = w * 4 + c;
      int row = ch * 8 + (l >> 3);
      async16(xb + (size_t)(b0 + row) * D_SZ + kt * 64 + ((l & 7) ^ (l >> 3)) * 8,
              (char*)sA + ch * 1024);
    }
    __syncthreads();
#pragma unroll
    for (int h = 0; h < 2; ++h) {
      int ckA = h * 4 + quad;
      bf16x8 af[2], bw[4];
#pragma unroll
      for (int i = 0; i < 2; ++i)
        af[i] = *(const bf16x8*)(sA + (size_t)(rbase + i * 16 + lane16) * 64 +
                                 (ckA ^ sw) * 8);
      int ckW = kt * 8 + h * 4 + quad;
#pragma unroll
      for (int j = 0; j < 4; ++j)
        bw[j] = *(const bf16x8*)(sW + (size_t)(j * 16 + lane16) * 512 +
                                 (ckW ^ sw) * 8);
#pragma unroll
      for (int i = 0; i < 2; ++i)
#pragma unroll
        for (int j = 0; j < 4; ++j)
          acc[i][j] = __builtin_amdgcn_mfma_f32_16x16x32_bf16(af[i], bw[j],
                                                              acc[i][j], 0, 0, 0);
    }
  }
  float bc[4];
#pragma unroll
  for (int j = 0; j < 4; ++j) bc[j] = key_bias[j * 16 + lane16];
#pragma unroll
  for (int i = 0; i < 2; ++i)
#pragma unroll
    for (int r = 0; r < 4; ++r) {
      int row = b0 + rbase + i * 16 + quad * 4 + r;
#pragma unroll
      for (int j = 0; j < 4; ++j)
        keyv[(size_t)row * 64 + j * 16 + lane16] = acc[i][j][r] + bc[j];
    }
}

// ------- simT[m][b] = 1/(||keyv[b]-keys_m||+1) -------
__global__ __launch_bounds__(256) void sim_map(const float* __restrict__ keyv,
                                               const float* __restrict__ keys_map,
                                               float* __restrict__ simT) {
  __shared__ float kv[16 * 64];
  int t = threadIdx.x;
  int b0 = blockIdx.x * 16;
  ((float4*)kv)[t] = ((const float4*)(keyv + (size_t)b0 * 64))[t];
  __syncthreads();
  int row = t >> 4, m = t & 15;
  const float* kvr = kv + row * 64;
  const float* km = keys_map + m * 64;
  float d2 = 0.f;
#pragma unroll 8
  for (int k = 0; k < 64; ++k) {
    float df = kvr[k] - km[k];
    d2 += df * df;
  }
  simT[(size_t)m * B_SZ + b0 + row] = 1.0f / (sqrtf(d2) + 1.0f);
}

// ------- out init = (1/16) * sum_m simT[m][b] * biases[m][u] -------
__global__ __launch_bounds__(256) void bias_init(const float* __restrict__ simT,
                                                 const float* __restrict__ biases,
                                                 float* __restrict__ out) {
  int t = threadIdx.x;
  int b = blockIdx.x * 2 + (t >> 7);
  int u = (t & 127) * 4;
  float4 acc = {0.f, 0.f, 0.f, 0.f};
#pragma unroll
  for (int m = 0; m < M_SZ; ++m) {
    float s = simT[(size_t)m * B_SZ + b];
    float4 bv = *(const float4*)(biases + (size_t)m * U_SZ + u);
    acc.x += s * bv.x; acc.y += s * bv.y; acc.z += s * bv.z; acc.w += s * bv.w;
  }
  acc.x *= 0.0625f; acc.y *= 0.0625f; acc.z *= 0.0625f; acc.w *= 0.0625f;
  *(float4*)(out + (size_t)b * U_SZ + u) = acc;
}

// ---------------- main weighted GEMM ----------------
// 512 blocks = 64 bt(128 rows) x 4 ut(128 cols) x 2 ks(K half).
// kt outer / m inner: A fragments live in registers across all 16 modes.
// atomicAdd onto bias-initialized out.
__global__ __launch_bounds__(256, 2) void poly_gemm(
    const unsigned short* __restrict__ xb,  // [B][D] bf16
    const unsigned short* __restrict__ kT,  // [M][U][D] bf16
    const float* __restrict__ simT,         // [M][B]
    float* __restrict__ out) {              // [B][U]
  __shared__ unsigned short sA[128 * 64];  // 16 KB
  __shared__ unsigned short sB[128 * 64];  // 16 KB

  int t = threadIdx.x, w = t >> 6, l = t & 63;
  int bid = blockIdx.x;
  int ut = bid & 3, ks = (bid >> 2) & 1, bt = bid >> 3;
  int b0 = bt * 128, u0 = ut * 128, k0 = ks * 256;

  int wi = w >> 1, wj = w & 1;  // 2x2 wave grid, each 64x64
  int rbase = wi * 64, cbase = wj * 64;
  int lane16 = l & 15, quad = l >> 4, sw = lane16 & 7;
  int srow = (l >> 3);          // staging row-in-chunk
  int skk = ((l & 7) ^ srow) * 8;  // swizzled source k-offset (elems)

  f32x4 facc[4][4];
#pragma unroll
  for (int i = 0; i < 4; ++i)
#pragma unroll
    for (int j = 0; j < 4; ++j) facc[i][j] = (f32x4){0.f, 0.f, 0.f, 0.f};

  const unsigned short* asrc = xb + (size_t)b0 * D_SZ + k0;
  const unsigned short* bsrc0 = kT + (size_t)u0 * D_SZ + k0;

  for (int kt = 0; kt < 4; ++kt) {
    int kk = kt * 64;
    __syncthreads();  // (C) all prior LDS reads done
    // stage A(kt) + B(kt, m=0)
#pragma unroll
    for (int c = 0; c < 4; ++c) {
      int ch = w * 4 + c;
      int row = ch * 8 + srow;
      async16(asrc + (size_t)row * D_SZ + kk + skk, (char*)sA + ch * 1024);
      async16(bsrc0 + (size_t)row * D_SZ + kk + skk, (char*)sB + ch * 1024);
    }
    __syncthreads();  // (D) staging done
    // A fragments -> registers, reused across all 16 modes
    bf16x8 af[4][2];
#pragma unroll
    for (int i = 0; i < 4; ++i)
#pragma unroll
      for (int h = 0; h < 2; ++h) {
        int ck = h * 4 + quad;
        af[i][h] = *(const bf16x8*)(sA + (size_t)(rbase + i * 16 + lane16) * 64 +
                                    (ck ^ sw) * 8);
      }
    for (int m = 0; m < M_SZ; ++m) {
      __syncthreads();  // (A) staging of B(m) complete (drain hidden under MFMA)
      bf16x8 bfr[4][2];
#pragma unroll
      for (int j = 0; j < 4; ++j)
#pragma unroll
        for (int h = 0; h < 2; ++h) {
          int ck = h * 4 + quad;
          bfr[j][h] = *(const bf16x8*)(sB + (size_t)(cbase + j * 16 + lane16) * 64 +
                                       (ck ^ sw) * 8);
        }
      __syncthreads();  // (B) all waves done reading sB -> safe to overwrite
      // sim fragments (L1-hot global; latency hidden under MFMA)
      f32x4 sv[4];
#pragma unroll
      for (int i = 0; i < 4; ++i)
        sv[i] = *(const f32x4*)(simT + (size_t)m * B_SZ + b0 + rbase + i * 16 +
                                quad * 4);
      // prefetch B(m+1) under the MFMA block
      if (m < 15) {
        const unsigned short* bsrc =
            kT + ((size_t)(m + 1) * U_SZ + u0) * D_SZ + k0;
#pragma unroll
        for (int c = 0; c < 4; ++c) {
          int ch = w * 4 + c;
          int row = ch * 8 + srow;
          async16(bsrc + (size_t)row * D_SZ + kk + skk, (char*)sB + ch * 1024);
        }
      }
#pragma unroll
      for (int jh = 0; jh < 2; ++jh) {
        f32x4 pacc[4][2];
#pragma unroll
        for (int i = 0; i < 4; ++i)
#pragma unroll
          for (int j2 = 0; j2 < 2; ++j2) {
            int j = jh * 2 + j2;
            pacc[i][j2] = __builtin_amdgcn_mfma_f32_16x16x32_bf16(
                af[i][0], bfr[j][0], (f32x4){0.f, 0.f, 0.f, 0.f}, 0, 0, 0);
            pacc[i][j2] = __builtin_amdgcn_mfma_f32_16x16x32_bf16(
                af[i][1], bfr[j][1], pacc[i][j2], 0, 0, 0);
          }
#pragma unroll
        for (int i = 0; i < 4; ++i)
#pragma unroll
          for (int j2 = 0; j2 < 2; ++j2)
#pragma unroll
            for (int r = 0; r < 4; ++r)
              facc[i][jh * 2 + j2][r] += sv[i][r] * pacc[i][j2][r];
      }
    }
  }

  // epilogue: atomic accumulate (two ks halves combine)
#pragma unroll
  for (int i = 0; i < 4; ++i)
#pragma unroll
    for (int r = 0; r < 4; ++r) {
      int row = b0 + rbase + i * 16 + quad * 4 + r;
#pragma unroll
      for (int j = 0; j < 4; ++j)
        atomicAdd(out + (size_t)row * U_SZ + u0 + cbase + j * 16 + lane16,
                  facc[i][j][r] * 0.0625f);
    }
}

extern "C" void kernel_launch(void* const* d_in, const int* in_sizes, int n_in,
                              void* d_out, int out_size, void* d_ws, size_t ws_size,
                              hipStream_t stream) {
  const float* x = (const float*)d_in[0];
  const float* key_kernel = (const float*)d_in[1];
  const float* key_bias = (const float*)d_in[2];
  const float* keys_map = (const float*)d_in[3];
  const float* kernels = (const float*)d_in[4];
  const float* biases = (const float*)d_in[5];
  float* out = (float*)d_out;

  // ws: xb 8MB | kT 8MB | wkT 64KB | keyv 2MB | simT 512KB  (~18.6 MB)
  char* p = (char*)d_ws;
  unsigned short* xb = (unsigned short*)p;            p += (size_t)B_SZ * D_SZ * 2;
  unsigned short* kT = (unsigned short*)p;            p += (size_t)M_SZ * U_SZ * D_SZ * 2;
  unsigned short* wkT = (unsigned short*)p;           p += (size_t)K_SZ * D_SZ * 2;
  float* keyv = (float*)p;                            p += (size_t)B_SZ * K_SZ * 4;
  float* simT = (float*)p;

  cvt_x<<<dim3((B_SZ * D_SZ) / 1024), 256, 0, stream>>>(x, xb);
  cvt_tr<<<dim3(U_SZ / 64, D_SZ / 32, M_SZ), 256, 0, stream>>>(kernels, kT,
                                                               D_SZ, U_SZ);
  cvt_tr<<<dim3(1, D_SZ / 32, 1), 256, 0, stream>>>(key_kernel, wkT, D_SZ, K_SZ);
  keyv_gemm<<<dim3(B_SZ / 128), 256, 0, stream>>>(xb, wkT, key_bias, keyv);
  sim_map<<<dim3(B_SZ / 16), 256, 0, stream>>>(keyv, keys_map, simT);
  bias_init<<<dim3(B_SZ / 2), 256, 0, stream>>>(simT, biases, out);
  poly_gemm<<<dim3(512), 256, 0, stream>>>(xb, kT, simT, out);
}